// Round 2
// baseline (546.690 us; speedup 1.0000x reference)
//
#include <hip/hip_runtime.h>

// Problem constants (shapes fixed by setup_inputs): nw_out [N=4, C=19, H=512, W=1024] fp32.
#define N_IMG 4
#define C_CLS 19
#define HW    (512 * 1024)          // per-image, per-channel plane
#define NPIX  (N_IMG * HW)          // 2,097,152 pixels
#define VPIX  (NPIX / 4)            // 524,288 float4 pixel-groups
#define NBLK  (VPIX / 256)          // 2,048 blocks
#define IW    0.2f

typedef float f4 __attribute__((ext_vector_type(4)));

// ws layout: [0..18] gsum, [19..37] gcnt, [38] ticket (as unsigned)
// ---------------------------------------------------------------------------
// Kernel 1: zero the 39-float workspace header (harness poisons d_ws each call).
// ---------------------------------------------------------------------------
__global__ void zero_ws(float* ws) {
    int t = threadIdx.x;
    if (t < 2 * C_CLS + 1) ws[t] = 0.0f;
}

// ---------------------------------------------------------------------------
// Kernel 2: batch-load single pass + fused last-block finalize.
//
// MLP lesson from round 1: the 19-channel burst of independent dwordx4 loads
// (76 VGPRs of val[]) IS the memory parallelism — 19 KB in flight per wave.
// The online-softmax variant (20 VGPRs, 18-deep serial load chain) collapsed
// to 255 GB/s. Keep the burst; spend registers on it.
//
// Per pixel: argmax class (first-max, matches jnp.argmax), stable
// s = sum(prob^2) = (sum e^2) / (sum e)^2 with e = exp(x - max).
// Accumulate per-class {sum s, count} in LDS, 19+19 global atomics per block,
// last-finished block (device-scope ticket) computes den_c and the scalar out.
// ---------------------------------------------------------------------------
__global__ __launch_bounds__(256, 4) void fused_pass(const float* __restrict__ x,
                                                     float* __restrict__ ws,
                                                     float* __restrict__ out) {
    float* gsum = ws;
    float* gcnt = ws + C_CLS;

    __shared__ float s_sum[C_CLS];
    __shared__ float s_cnt[C_CLS];
    __shared__ int   s_last;

    const int t = threadIdx.x;
    if (t < C_CLS) { s_sum[t] = 0.0f; s_cnt[t] = 0.0f; }
    __syncthreads();

    // vec4 pixel-group index; grid exactly covers VPIX (2048 blocks * 256).
    const int v   = blockIdx.x * 256 + t;
    const int n   = v >> 17;                 // HW/4 = 131072 = 2^17
    const int hw4 = v & (131072 - 1);
    const float* base = x + (size_t)n * C_CLS * HW + (size_t)hw4 * 4;

    // Burst-load all 19 channels x 4 pixels (19 independent dwordx4 in flight).
    f4 val[C_CLS];
#pragma unroll
    for (int c = 0; c < C_CLS; ++c)
        val[c] = *(const f4*)(base + (size_t)c * HW);

#pragma unroll
    for (int j = 0; j < 4; ++j) {
        // argmax (first-max semantics) + max for numerical stability
        float m = val[0][j];
        int   am = 0;
#pragma unroll
        for (int c = 1; c < C_CLS; ++c) {
            float xv = val[c][j];
            if (xv > m) { m = xv; am = c; }
        }
        // l = sum exp(x-m), q = sum exp(x-m)^2 ; s = q / l^2 = sum(prob^2)
        float l = 0.0f, q = 0.0f;
#pragma unroll
        for (int c = 0; c < C_CLS; ++c) {
            float e = __expf(val[c][j] - m);
            l += e;
            q += e * e;
        }
        float s = q / (l * l);
        atomicAdd(&s_sum[am], s);
        atomicAdd(&s_cnt[am], 1.0f);   // exact: integer-valued fp32 < 2^24
    }

    __syncthreads();
    if (t < C_CLS) {
        atomicAdd(&gsum[t], s_sum[t]);
        atomicAdd(&gcnt[t], s_cnt[t]);
    }
    __threadfence();                          // make this block's adds device-visible
    __syncthreads();

    if (t == 0) {
        unsigned* ticket = (unsigned*)(ws + 2 * C_CLS);
        unsigned old = atomicAdd(ticket, 1u); // device-scope; no dispatch-order assumption
        s_last = (old == (unsigned)(NBLK - 1)) ? 1 : 0;
    }
    __syncthreads();

    if (s_last && t < 64) {
        float vsum = 0.0f;
        if (t < C_CLS) {
            // atomic reads: L2-coherent path, immune to any stale-L1 concern
            float cnt = atomicAdd(&gcnt[t], 0.0f);
            float sm  = atomicAdd(&gsum[t], 0.0f);
            const float scale = powf((float)NPIX, 1.0f - IW);     // Np^0.8
            float den = fmaxf(powf(cnt, IW) * scale, 1.0f);
            vsum = sm / den;
        }
#pragma unroll
        for (int off = 32; off > 0; off >>= 1)
            vsum += __shfl_down(vsum, off);
        if (t == 0)
            out[0] = -vsum / (float)(N_IMG * C_CLS);
    }
}

extern "C" void kernel_launch(void* const* d_in, const int* in_sizes, int n_in,
                              void* d_out, int out_size, void* d_ws, size_t ws_size,
                              hipStream_t stream) {
    const float* x = (const float*)d_in[0];
    float* ws = (float*)d_ws;

    zero_ws<<<1, 64, 0, stream>>>(ws);
    fused_pass<<<NBLK, 256, 0, stream>>>(x, ws, (float*)d_out);
}

// Round 4
// 238.855 us; speedup vs baseline: 2.2888x; 2.2888x over previous
//
#include <hip/hip_runtime.h>

// Problem constants (shapes fixed by setup_inputs): nw_out [N=4, C=19, H=512, W=1024] fp32.
#define N_IMG 4
#define C_CLS 19
#define HW    (512 * 1024)          // per-image, per-channel plane
#define NPIX  (N_IMG * HW)          // 2,097,152 pixels
#define VPIX  (NPIX / 4)            // 524,288 float4 pixel-groups
#define NBLK  (VPIX / 256)          // 2,048 blocks
#define IW    0.2f

typedef float f4 __attribute__((ext_vector_type(4)));

// ---------------------------------------------------------------------------
// Kernel 1: zero the 2*C_CLS float workspace (harness poisons d_ws each call).
// ---------------------------------------------------------------------------
__global__ void zero_ws(float* ws) {
    int t = threadIdx.x;
    if (t < 2 * C_CLS) ws[t] = 0.0f;
}

// ---------------------------------------------------------------------------
// Kernel 2: single full pass.
//
// Round-2 lesson (VGPR_Count=40 smoking gun): writing a source-level burst of
// 19 loads is NOT enough — the compiler sinks each load to its first use in
// the serial argmax chain, collapsing MLP to ~2 loads in flight (203 GB/s).
// Fix: sched_barrier(0) after the loads + asm "+v" pin on every val[c], which
// (a) forbids sinking loads past the barrier and (b) makes each value
// "redefined" so it cannot be rematerialized — all 19 float4 stay live
// => 19 independent global_load_dwordx4 in flight per wave (19 KB MLP).
//
// Post-load critical path shortened: 5-deep fmax tree for the row max, then
// first-max argmax via ascending equality select (exact: fmax returns one of
// its inputs bitwise; no NaNs in the input distribution; ties pick smallest
// index = jnp.argmax first-max semantics).
// ---------------------------------------------------------------------------
__global__ __launch_bounds__(256) void main_pass(const float* __restrict__ x,
                                                 float* __restrict__ gsum,
                                                 float* __restrict__ gcnt) {
    __shared__ float s_sum[C_CLS];
    __shared__ float s_cnt[C_CLS];
    const int t = threadIdx.x;
    if (t < C_CLS) { s_sum[t] = 0.0f; s_cnt[t] = 0.0f; }
    __syncthreads();

    // vec4 pixel-group index; grid exactly covers VPIX (2048 blocks * 256).
    const int v   = blockIdx.x * 256 + t;
    const int n   = v >> 17;                 // HW/4 = 131072 = 2^17
    const int hw4 = v & (131072 - 1);
    const float* base = x + (size_t)n * C_CLS * HW + (size_t)hw4 * 4;

    // Burst-load all 19 channels x 4 pixels.
    f4 val[C_CLS];
#pragma unroll
    for (int c = 0; c < C_CLS; ++c)
        val[c] = *(const f4*)(base + (size_t)c * HW);

    // Pin the burst: nothing crosses; every val[c] forced live in VGPRs here.
    __builtin_amdgcn_sched_barrier(0);
#pragma unroll
    for (int c = 0; c < C_CLS; ++c)
        asm volatile("" : "+v"(val[c]));

#pragma unroll
    for (int j = 0; j < 4; ++j) {
        // row max via 5-deep tree (compiler may fuse pairs into v_max3)
        float a0 = fmaxf(val[0][j],  val[1][j]);
        float a1 = fmaxf(val[2][j],  val[3][j]);
        float a2 = fmaxf(val[4][j],  val[5][j]);
        float a3 = fmaxf(val[6][j],  val[7][j]);
        float a4 = fmaxf(val[8][j],  val[9][j]);
        float a5 = fmaxf(val[10][j], val[11][j]);
        float a6 = fmaxf(val[12][j], val[13][j]);
        float a7 = fmaxf(val[14][j], val[15][j]);
        float a8 = fmaxf(val[16][j], val[17][j]);
        float b0 = fmaxf(a0, a1);
        float b1 = fmaxf(a2, a3);
        float b2 = fmaxf(a4, a5);
        float b3 = fmaxf(a6, a7);
        float b4 = fmaxf(a8, val[18][j]);
        float m  = fmaxf(fmaxf(fmaxf(b0, b1), fmaxf(b2, b3)), b4);

        // first-max argmax: smallest c with val[c] == m
        int am = 18;
#pragma unroll
        for (int c = 17; c >= 0; --c)
            am = (val[c][j] == m) ? c : am;

        // l = sum exp(x-m), q = sum exp(x-m)^2 ; s = q / l^2 = sum(prob^2)
        float l = 0.0f, q = 0.0f;
#pragma unroll
        for (int c = 0; c < C_CLS; ++c) {
            float e = __expf(val[c][j] - m);
            l += e;
            q += e * e;
        }
        float s = q / (l * l);
        atomicAdd(&s_sum[am], s);
        atomicAdd(&s_cnt[am], 1.0f);   // exact: integer-valued fp32 < 2^24
    }

    __syncthreads();
    if (t < C_CLS) {
        atomicAdd(&gsum[t], s_sum[t]);
        atomicAdd(&gcnt[t], s_cnt[t]);
    }
}

// ---------------------------------------------------------------------------
// Kernel 3: den_c = max(hist^0.2 * Np^0.8, 1); out = -sum_c(gsum[c]/den_c)/(N*C)
// ---------------------------------------------------------------------------
__global__ void finalize(const float* __restrict__ gsum,
                         const float* __restrict__ gcnt,
                         float* __restrict__ out) {
    const int t = threadIdx.x;   // one wave of 64
    float vsum = 0.0f;
    if (t < C_CLS) {
        const float scale = powf((float)NPIX, 1.0f - IW);   // Np^0.8
        float den = fmaxf(powf(gcnt[t], IW) * scale, 1.0f);
        vsum = gsum[t] / den;
    }
#pragma unroll
    for (int off = 32; off > 0; off >>= 1)
        vsum += __shfl_down(vsum, off);
    if (t == 0)
        out[0] = -vsum / (float)(N_IMG * C_CLS);
}

extern "C" void kernel_launch(void* const* d_in, const int* in_sizes, int n_in,
                              void* d_out, int out_size, void* d_ws, size_t ws_size,
                              hipStream_t stream) {
    const float* x = (const float*)d_in[0];
    float* out  = (float*)d_out;
    float* gsum = (float*)d_ws;          // [C_CLS]
    float* gcnt = gsum + C_CLS;          // [C_CLS]

    zero_ws<<<1, 64, 0, stream>>>(gsum);
    main_pass<<<NBLK, 256, 0, stream>>>(x, gsum, gcnt);
    finalize<<<1, 64, 0, stream>>>(gsum, gcnt, out);
}

// Round 5
// 221.903 us; speedup vs baseline: 2.4636x; 1.0764x over previous
//
#include <hip/hip_runtime.h>

// Problem constants (shapes fixed by setup_inputs): nw_out [N=4, C=19, H=512, W=1024] fp32.
#define N_IMG 4
#define C_CLS 19
#define HW    (512 * 1024)          // per-image, per-channel plane
#define NPIX  (N_IMG * HW)          // 2,097,152 pixels
#define VPIX  (NPIX / 4)            // 524,288 float4 pixel-groups
#define NBLK  (VPIX / 256)          // 2,048 blocks
#define NCOL  (2 * C_CLS)           // 38 scratch columns (19 sums + 19 counts)
#define IW    0.2f

typedef float f4 __attribute__((ext_vector_type(4)));

// ---------------------------------------------------------------------------
// Kernel 1: single full pass over the input.
//
// Round-4 lesson: with the pinned 19-load burst the total did NOT move
// (238.9 vs 240.0) — the constant across every experiment is the epilogue:
// 2048 blocks x 38 device-scope atomicAdds onto the SAME 1-2 cache lines
// (~78K serialized lane-atomics through one coherence point, cross-XCD).
// This round removes that tail: per-block partials go to scratch[38][2048]
// with plain scattered stores (no contention, no zero_ws needed — scratch is
// fully overwritten). Kernel-boundary release/acquire makes the writes
// visible to the next dispatch without fences.
//
// Streaming body unchanged from round 4 (pinned burst, max tree, equality
// argmax, single-pass l/q accumulation).
// ---------------------------------------------------------------------------
__global__ __launch_bounds__(256) void main_pass(const float* __restrict__ x,
                                                 float* __restrict__ scratch) {
    __shared__ float s_sum[C_CLS];
    __shared__ float s_cnt[C_CLS];
    const int t = threadIdx.x;
    if (t < C_CLS) { s_sum[t] = 0.0f; s_cnt[t] = 0.0f; }
    __syncthreads();

    // vec4 pixel-group index; grid exactly covers VPIX (2048 blocks * 256).
    const int v   = blockIdx.x * 256 + t;
    const int n   = v >> 17;                 // HW/4 = 131072 = 2^17
    const int hw4 = v & (131072 - 1);
    const float* base = x + (size_t)n * C_CLS * HW + (size_t)hw4 * 4;

    // Burst-load all 19 channels x 4 pixels.
    f4 val[C_CLS];
#pragma unroll
    for (int c = 0; c < C_CLS; ++c)
        val[c] = *(const f4*)(base + (size_t)c * HW);

    // Pin the burst: nothing crosses; every val[c] forced live in VGPRs here.
    __builtin_amdgcn_sched_barrier(0);
#pragma unroll
    for (int c = 0; c < C_CLS; ++c)
        asm volatile("" : "+v"(val[c]));

#pragma unroll
    for (int j = 0; j < 4; ++j) {
        // row max via 5-deep tree (compiler may fuse pairs into v_max3)
        float a0 = fmaxf(val[0][j],  val[1][j]);
        float a1 = fmaxf(val[2][j],  val[3][j]);
        float a2 = fmaxf(val[4][j],  val[5][j]);
        float a3 = fmaxf(val[6][j],  val[7][j]);
        float a4 = fmaxf(val[8][j],  val[9][j]);
        float a5 = fmaxf(val[10][j], val[11][j]);
        float a6 = fmaxf(val[12][j], val[13][j]);
        float a7 = fmaxf(val[14][j], val[15][j]);
        float a8 = fmaxf(val[16][j], val[17][j]);
        float b0 = fmaxf(a0, a1);
        float b1 = fmaxf(a2, a3);
        float b2 = fmaxf(a4, a5);
        float b3 = fmaxf(a6, a7);
        float b4 = fmaxf(a8, val[18][j]);
        float m  = fmaxf(fmaxf(fmaxf(b0, b1), fmaxf(b2, b3)), b4);

        // first-max argmax: smallest c with val[c] == m (fmax returns an
        // input bitwise; no NaNs in input; ties pick smallest index)
        int am = 18;
#pragma unroll
        for (int c = 17; c >= 0; --c)
            am = (val[c][j] == m) ? c : am;

        // l = sum exp(x-m), q = sum exp(x-m)^2 ; s = q / l^2 = sum(prob^2)
        float l = 0.0f, q = 0.0f;
#pragma unroll
        for (int c = 0; c < C_CLS; ++c) {
            float e = __expf(val[c][j] - m);
            l += e;
            q += e * e;
        }
        float s = q / (l * l);
        atomicAdd(&s_sum[am], s);
        atomicAdd(&s_cnt[am], 1.0f);   // exact: integer-valued fp32 < 2^24
    }

    __syncthreads();
    // Column-major scratch[c][b]: 38 scattered dword stores per block, all to
    // distinct lines per column — zero contention, no atomics.
    if (t < NCOL)
        scratch[t * NBLK + blockIdx.x] = (t < C_CLS) ? s_sum[t] : s_cnt[t - C_CLS];
}

// ---------------------------------------------------------------------------
// Kernel 2: reduce scratch[38][2048] + finalize, one block of 1024 (16 waves).
// Wave w sums columns {w, w+16, w+32<38} with float4 loads + shuffle reduce,
// then wave 0 computes den_c = max(hist^0.2 * Np^0.8, 1) and the scalar out.
// ---------------------------------------------------------------------------
__global__ __launch_bounds__(1024) void reduce_finalize(const float* __restrict__ scratch,
                                                        float* __restrict__ out) {
    __shared__ float tot[NCOL];
    const int t    = threadIdx.x;
    const int wave = t >> 6;
    const int lane = t & 63;

    for (int c = wave; c < NCOL; c += 16) {
        const f4* col = (const f4*)(scratch + (size_t)c * NBLK);  // 512 float4
        float acc = 0.0f;
#pragma unroll
        for (int k = 0; k < 8; ++k) {
            f4 vv = col[k * 64 + lane];
            acc += (vv[0] + vv[1]) + (vv[2] + vv[3]);
        }
#pragma unroll
        for (int off = 32; off > 0; off >>= 1)
            acc += __shfl_down(acc, off);
        if (lane == 0) tot[c] = acc;
    }
    __syncthreads();

    if (t < 64) {
        float vsum = 0.0f;
        if (t < C_CLS) {
            const float scale = powf((float)NPIX, 1.0f - IW);   // Np^0.8
            float den = fmaxf(powf(tot[C_CLS + t], IW) * scale, 1.0f);
            vsum = tot[t] / den;
        }
#pragma unroll
        for (int off = 32; off > 0; off >>= 1)
            vsum += __shfl_down(vsum, off);
        if (t == 0)
            out[0] = -vsum / (float)(N_IMG * C_CLS);
    }
}

extern "C" void kernel_launch(void* const* d_in, const int* in_sizes, int n_in,
                              void* d_out, int out_size, void* d_ws, size_t ws_size,
                              hipStream_t stream) {
    const float* x = (const float*)d_in[0];
    float* scratch = (float*)d_ws;       // [38][2048] floats = 311 KB, fully overwritten

    main_pass<<<NBLK, 256, 0, stream>>>(x, scratch);
    reduce_finalize<<<1, 1024, 0, stream>>>(scratch, (float*)d_out);
}

// Round 6
// 220.725 us; speedup vs baseline: 2.4768x; 1.0053x over previous
//
#include <hip/hip_runtime.h>

// Problem constants (shapes fixed by setup_inputs): nw_out [N=4, C=19, H=512, W=1024] fp32.
#define N_IMG 4
#define C_CLS 19
#define HW    (512 * 1024)          // per-image, per-channel plane
#define NPIX  (N_IMG * HW)          // 2,097,152 pixels
#define VPIX  (NPIX / 4)            // 524,288 float4 pixel-groups
#define NBLK  (VPIX / 256)          // 2,048 blocks
#define NCOL  (2 * C_CLS)           // 38 scratch columns (19 sums + 19 counts)
#define IW    0.2f

typedef float f4 __attribute__((ext_vector_type(4)));

// ---------------------------------------------------------------------------
// Kernel 1: single full pass over the input. UNCHANGED from round 5 (proven:
// pinned 19-load burst + LDS histogram + zero-contention scratch stores).
// ---------------------------------------------------------------------------
__global__ __launch_bounds__(256) void main_pass(const float* __restrict__ x,
                                                 float* __restrict__ scratch) {
    __shared__ float s_sum[C_CLS];
    __shared__ float s_cnt[C_CLS];
    const int t = threadIdx.x;
    if (t < C_CLS) { s_sum[t] = 0.0f; s_cnt[t] = 0.0f; }
    __syncthreads();

    // vec4 pixel-group index; grid exactly covers VPIX (2048 blocks * 256).
    const int v   = blockIdx.x * 256 + t;
    const int n   = v >> 17;                 // HW/4 = 131072 = 2^17
    const int hw4 = v & (131072 - 1);
    const float* base = x + (size_t)n * C_CLS * HW + (size_t)hw4 * 4;

    // Burst-load all 19 channels x 4 pixels.
    f4 val[C_CLS];
#pragma unroll
    for (int c = 0; c < C_CLS; ++c)
        val[c] = *(const f4*)(base + (size_t)c * HW);

    // Pin the burst: nothing crosses; every val[c] forced live in VGPRs here.
    // (r2 vs r4 evidence: without this, the fused/epilogue variants compiled
    // to a serialized load chain — 395 us vs ~92 us.)
    __builtin_amdgcn_sched_barrier(0);
#pragma unroll
    for (int c = 0; c < C_CLS; ++c)
        asm volatile("" : "+v"(val[c]));

#pragma unroll
    for (int j = 0; j < 4; ++j) {
        // row max via 5-deep tree (compiler may fuse pairs into v_max3)
        float a0 = fmaxf(val[0][j],  val[1][j]);
        float a1 = fmaxf(val[2][j],  val[3][j]);
        float a2 = fmaxf(val[4][j],  val[5][j]);
        float a3 = fmaxf(val[6][j],  val[7][j]);
        float a4 = fmaxf(val[8][j],  val[9][j]);
        float a5 = fmaxf(val[10][j], val[11][j]);
        float a6 = fmaxf(val[12][j], val[13][j]);
        float a7 = fmaxf(val[14][j], val[15][j]);
        float a8 = fmaxf(val[16][j], val[17][j]);
        float b0 = fmaxf(a0, a1);
        float b1 = fmaxf(a2, a3);
        float b2 = fmaxf(a4, a5);
        float b3 = fmaxf(a6, a7);
        float b4 = fmaxf(a8, val[18][j]);
        float m  = fmaxf(fmaxf(fmaxf(b0, b1), fmaxf(b2, b3)), b4);

        // first-max argmax: smallest c with val[c] == m (fmax returns an
        // input bitwise; no NaNs in input; ties pick smallest index)
        int am = 18;
#pragma unroll
        for (int c = 17; c >= 0; --c)
            am = (val[c][j] == m) ? c : am;

        // l = sum exp(x-m), q = sum exp(x-m)^2 ; s = q / l^2 = sum(prob^2)
        float l = 0.0f, q = 0.0f;
#pragma unroll
        for (int c = 0; c < C_CLS; ++c) {
            float e = __expf(val[c][j] - m);
            l += e;
            q += e * e;
        }
        float s = q / (l * l);
        atomicAdd(&s_sum[am], s);
        atomicAdd(&s_cnt[am], 1.0f);   // exact: integer-valued fp32 < 2^24
    }

    __syncthreads();
    // Column-major scratch[c][b]: 38 scattered dword stores per block, all to
    // distinct lines per column — zero contention, no atomics.
    if (t < NCOL)
        scratch[t * NBLK + blockIdx.x] = (t < C_CLS) ? s_sum[t] : s_cnt[t - C_CLS];
}

// ---------------------------------------------------------------------------
// Kernel 2: parallel column reduction. Round-5's single-block reducer pulled
// 311 KB of dirty lines out of 8 remote XCD L2s through one CU (latency-bound,
// zero parallelism). Now: 38 blocks, one per column, spread across CUs/XCDs —
// each block sums 2048 contiguous floats (coalesced f4) and writes tot[c].
// ---------------------------------------------------------------------------
__global__ __launch_bounds__(256) void colsum(const float* __restrict__ scratch,
                                              float* __restrict__ tot) {
    __shared__ float wsum[4];
    const int c    = blockIdx.x;             // 0..37
    const int t    = threadIdx.x;
    const int wave = t >> 6;
    const int lane = t & 63;

    const f4* col = (const f4*)(scratch + (size_t)c * NBLK);  // 512 float4
    f4 v0 = col[wave * 128 + lane];
    f4 v1 = col[wave * 128 + 64 + lane];
    float acc = ((v0[0] + v0[1]) + (v0[2] + v0[3]))
              + ((v1[0] + v1[1]) + (v1[2] + v1[3]));
#pragma unroll
    for (int off = 32; off > 0; off >>= 1)
        acc += __shfl_down(acc, off);
    if (lane == 0) wsum[wave] = acc;
    __syncthreads();
    if (t == 0)
        tot[c] = (wsum[0] + wsum[1]) + (wsum[2] + wsum[3]);
}

// ---------------------------------------------------------------------------
// Kernel 3: den_c = max(hist^0.2 * Np^0.8, 1); out = -sum_c(tot[c]/den_c)/(N*C)
// ---------------------------------------------------------------------------
__global__ void finalize(const float* __restrict__ tot,
                         float* __restrict__ out) {
    const int t = threadIdx.x;   // one wave of 64
    float vsum = 0.0f;
    if (t < C_CLS) {
        const float scale = powf((float)NPIX, 1.0f - IW);   // Np^0.8
        float den = fmaxf(powf(tot[C_CLS + t], IW) * scale, 1.0f);
        vsum = tot[t] / den;
    }
#pragma unroll
    for (int off = 32; off > 0; off >>= 1)
        vsum += __shfl_down(vsum, off);
    if (t == 0)
        out[0] = -vsum / (float)(N_IMG * C_CLS);
}

extern "C" void kernel_launch(void* const* d_in, const int* in_sizes, int n_in,
                              void* d_out, int out_size, void* d_ws, size_t ws_size,
                              hipStream_t stream) {
    const float* x = (const float*)d_in[0];
    float* scratch = (float*)d_ws;            // [38][2048] floats = 311 KB
    float* tot     = scratch + NCOL * NBLK;   // [38] floats

    main_pass<<<NBLK, 256, 0, stream>>>(x, scratch);
    colsum<<<NCOL, 256, 0, stream>>>(scratch, tot);
    finalize<<<1, 64, 0, stream>>>(tot, (float*)d_out);
}

// Round 7
// 220.138 us; speedup vs baseline: 2.4834x; 1.0027x over previous
//
#include <hip/hip_runtime.h>

// Problem constants (shapes fixed by setup_inputs): nw_out [N=4, C=19, H=512, W=1024] fp32.
#define N_IMG 4
#define C_CLS 19
#define HW    (512 * 1024)          // per-image, per-channel plane
#define NPIX  (N_IMG * HW)          // 2,097,152 pixels
#define VPIX2 (NPIX / 2)            // 1,048,576 float2 pixel-groups
#define NBLK  (VPIX2 / 256)         // 4,096 blocks
#define NCOL  (2 * C_CLS)           // 38 scratch columns (19 sums + 19 counts)
#define IW    0.2f

typedef float f2 __attribute__((ext_vector_type(2)));
typedef float f4 __attribute__((ext_vector_type(4)));

// ---------------------------------------------------------------------------
// Kernel 1: single full pass over the input.
//
// Round-6 lesson: reducer was already cheap; main_pass (~67 us) is 3x its
// ~24 us memory floor. Candidate cause: val[19] of float4 = 76+ VGPR keeps
// only 2 waves/SIMD resident — not enough TLP to cover the 900-cy load burst
// plus the quarter-rate exp chain. This round: 2 pixels/thread (float2), so
// val[] = 38 VGPR, ~64 total -> 4-8 waves/SIMD, 4096 blocks, dwordx2 loads.
// Math per pixel is bit-identical to rounds 4-6 (absmax must stay 0).
// ---------------------------------------------------------------------------
__global__ __launch_bounds__(256) void main_pass(const float* __restrict__ x,
                                                 float* __restrict__ scratch) {
    __shared__ float s_sum[C_CLS];
    __shared__ float s_cnt[C_CLS];
    const int t = threadIdx.x;
    if (t < C_CLS) { s_sum[t] = 0.0f; s_cnt[t] = 0.0f; }
    __syncthreads();

    // f2 pixel-group index; grid exactly covers VPIX2 (4096 blocks * 256).
    const int v   = blockIdx.x * 256 + t;
    const int n   = v >> 18;                 // HW/2 = 262144 = 2^18
    const int hw2 = v & (262144 - 1);
    const float* base = x + (size_t)n * C_CLS * HW + (size_t)hw2 * 2;

    // Burst-load all 19 channels x 2 pixels (19 independent dwordx2).
    f2 val[C_CLS];
#pragma unroll
    for (int c = 0; c < C_CLS; ++c)
        val[c] = *(const f2*)(base + (size_t)c * HW);

    // Pin the burst: nothing crosses; every val[c] forced live in VGPRs here.
    // (r2-vs-r4 evidence: without this the loads compile to a serial chain.)
    __builtin_amdgcn_sched_barrier(0);
#pragma unroll
    for (int c = 0; c < C_CLS; ++c)
        asm volatile("" : "+v"(val[c]));

#pragma unroll
    for (int j = 0; j < 2; ++j) {
        // row max via 5-deep tree (compiler may fuse pairs into v_max3)
        float a0 = fmaxf(val[0][j],  val[1][j]);
        float a1 = fmaxf(val[2][j],  val[3][j]);
        float a2 = fmaxf(val[4][j],  val[5][j]);
        float a3 = fmaxf(val[6][j],  val[7][j]);
        float a4 = fmaxf(val[8][j],  val[9][j]);
        float a5 = fmaxf(val[10][j], val[11][j]);
        float a6 = fmaxf(val[12][j], val[13][j]);
        float a7 = fmaxf(val[14][j], val[15][j]);
        float a8 = fmaxf(val[16][j], val[17][j]);
        float b0 = fmaxf(a0, a1);
        float b1 = fmaxf(a2, a3);
        float b2 = fmaxf(a4, a5);
        float b3 = fmaxf(a6, a7);
        float b4 = fmaxf(a8, val[18][j]);
        float m  = fmaxf(fmaxf(fmaxf(b0, b1), fmaxf(b2, b3)), b4);

        // first-max argmax: smallest c with val[c] == m (fmax returns an
        // input bitwise; no NaNs in input; ties pick smallest index)
        int am = 18;
#pragma unroll
        for (int c = 17; c >= 0; --c)
            am = (val[c][j] == m) ? c : am;

        // l = sum exp(x-m), q = sum exp(x-m)^2, split into even/odd partials
        // to halve the dependent-accumulate chain behind the exp pipe.
        float l0 = 0.0f, l1 = 0.0f, q0 = 0.0f, q1 = 0.0f;
#pragma unroll
        for (int c = 0; c < C_CLS; c += 2) {
            float e = __expf(val[c][j] - m);
            l0 += e; q0 += e * e;
        }
#pragma unroll
        for (int c = 1; c < C_CLS; c += 2) {
            float e = __expf(val[c][j] - m);
            l1 += e; q1 += e * e;
        }
        float l = l0 + l1, q = q0 + q1;
        float s = q / (l * l);
        atomicAdd(&s_sum[am], s);
        atomicAdd(&s_cnt[am], 1.0f);   // exact: integer-valued fp32 < 2^24
    }

    __syncthreads();
    // Column-major scratch[c][b]: 38 scattered dword stores per block, all to
    // distinct lines per column — zero contention, no atomics, no zero_ws.
    if (t < NCOL)
        scratch[t * NBLK + blockIdx.x] = (t < C_CLS) ? s_sum[t] : s_cnt[t - C_CLS];
}

// ---------------------------------------------------------------------------
// Kernel 2: parallel column reduction — 38 blocks, one per scratch column.
// Column = 4096 contiguous floats = 1024 f4; 256 threads x 4 f4 each.
// ---------------------------------------------------------------------------
__global__ __launch_bounds__(256) void colsum(const float* __restrict__ scratch,
                                              float* __restrict__ tot) {
    __shared__ float wsum[4];
    const int c    = blockIdx.x;             // 0..37
    const int t    = threadIdx.x;
    const int wave = t >> 6;
    const int lane = t & 63;

    const f4* col = (const f4*)(scratch + (size_t)c * NBLK);  // 1024 f4
    float acc = 0.0f;
#pragma unroll
    for (int k = 0; k < 4; ++k) {
        f4 vv = col[k * 256 + t];
        acc += (vv[0] + vv[1]) + (vv[2] + vv[3]);
    }
#pragma unroll
    for (int off = 32; off > 0; off >>= 1)
        acc += __shfl_down(acc, off);
    if (lane == 0) wsum[wave] = acc;
    __syncthreads();
    if (t == 0)
        tot[c] = (wsum[0] + wsum[1]) + (wsum[2] + wsum[3]);
}

// ---------------------------------------------------------------------------
// Kernel 3: den_c = max(hist^0.2 * Np^0.8, 1); out = -sum_c(tot[c]/den_c)/(N*C)
// ---------------------------------------------------------------------------
__global__ void finalize(const float* __restrict__ tot,
                         float* __restrict__ out) {
    const int t = threadIdx.x;   // one wave of 64
    float vsum = 0.0f;
    if (t < C_CLS) {
        const float scale = powf((float)NPIX, 1.0f - IW);   // Np^0.8
        float den = fmaxf(powf(tot[C_CLS + t], IW) * scale, 1.0f);
        vsum = tot[t] / den;
    }
#pragma unroll
    for (int off = 32; off > 0; off >>= 1)
        vsum += __shfl_down(vsum, off);
    if (t == 0)
        out[0] = -vsum / (float)(N_IMG * C_CLS);
}

extern "C" void kernel_launch(void* const* d_in, const int* in_sizes, int n_in,
                              void* d_out, int out_size, void* d_ws, size_t ws_size,
                              hipStream_t stream) {
    const float* x = (const float*)d_in[0];
    float* scratch = (float*)d_ws;            // [38][4096] floats = 622 KB
    float* tot     = scratch + (size_t)NCOL * NBLK;   // [38] floats

    main_pass<<<NBLK, 256, 0, stream>>>(x, scratch);
    colsum<<<NCOL, 256, 0, stream>>>(scratch, tot);
    finalize<<<1, 64, 0, stream>>>(tot, (float*)d_out);
}